// Round 26
// baseline (160.051 us; speedup 1.0000x reference)
//
#include <hip/hip_runtime.h>
#include <math.h>

#define CT    320
#define NPTS  1024
#define DFEAT 256
#define DPOS  64
#define KSEL  32

// ============ Kernel C: per-point 1/max(||pos||,eps) -> rnjg (ws) ===========
__global__ void gnn_rnj(const float* __restrict__ in, float* __restrict__ rnjg) {
  const int b     = blockIdx.x;
  const int batch = b >> 2;
  const int j     = ((b & 3) << 8) + threadIdx.x;
  const float* __restrict__ pbase = in + (size_t)batch * CT * NPTS + (size_t)DFEAT * NPTS;
  float s = 0.f;
#pragma unroll 8
  for (int d = 0; d < DPOS; ++d) {
    const float x = pbase[(size_t)d * NPTS + j];
    s = fmaf(x, x, s);
  }
  rnjg[batch * NPTS + j] = 1.0f / fmaxf(sqrtf(s), 1e-12f);
}

// ================= Kernel A: round-11 config FROZEN (best: 64 us) ===========
#define AROWS 16
#define DCH   2
#define QSTEP 6.103515625e-05f          // 2^-14, thr(m) = m*QSTEP - 1 (exact)
__global__ __launch_bounds__(256, 4) void gnn_sim_topk(const float* __restrict__ in,
                                                       const float* __restrict__ rnjg,
                                                       float2* __restrict__ pairs) {
  __shared__ float pi[DPOS * 20];
  __shared__ float rnjL[NPTS];
  __shared__ float jt[3][DCH * 1024];
  __shared__ float cand[AROWS][68];

  const int p     = blockIdx.x;
  const int batch = ((p & 7) << 1) | ((p >> 3) & 1);
  const int chunk = p >> 4;
  const int i0    = chunk * AROWS;
  const int tid   = threadIdx.x;
  const int w     = tid >> 6;
  const int lane  = tid & 63;

  const float* __restrict__ pbase = in + (size_t)batch * CT * NPTS + (size_t)DFEAT * NPTS;

  {
    const int i = tid & 15;
    const int d0 = tid >> 4;
#pragma unroll
    for (int pass = 0; pass < 4; ++pass) {
      const int d = pass * 16 + d0;
      pi[d * 20 + i] = pbase[(size_t)d * NPTS + i0 + i];
    }
  }
  *(float4*)&rnjL[tid * 4] = *(const float4*)&rnjg[batch * NPTS + tid * 4];

#define JSTAGE(buf, c)                                                           \
  do {                                                                           \
    const int dd_   = (w >> 1);                                                  \
    const int half_ = (w & 1);                                                   \
    const float* src_ = pbase + (size_t)((c) * DCH + dd_) * NPTS + half_ * 512 + lane * 4; \
    float* dst_ = &jt[buf][dd_ * 1024 + half_ * 512];                            \
    __builtin_amdgcn_global_load_lds(                                            \
        (const __attribute__((address_space(1))) void*)(src_),                   \
        (__attribute__((address_space(3))) void*)(dst_), 16, 0, 0);              \
    __builtin_amdgcn_global_load_lds(                                            \
        (const __attribute__((address_space(1))) void*)(src_ + 256),             \
        (__attribute__((address_space(3))) void*)(dst_ + 256), 16, 0, 0);        \
  } while (0)

  JSTAGE(0, 0);
  JSTAGE(1, 1);
  asm volatile("s_waitcnt vmcnt(2)" ::: "memory");
  __syncthreads();

  float acc[4][16];
#pragma unroll
  for (int r = 0; r < 4; ++r)
#pragma unroll
    for (int s = 0; s < 16; ++s) acc[r][s] = 0.f;

  int cur = 0;
  for (int c = 0; c < DPOS / DCH; ++c) {
#pragma unroll
    for (int dd = 0; dd < DCH; ++dd) {
      const int d = c * DCH + dd;
      const float4 pv4 = *(const float4*)&pi[d * 20 + w * 4];
      const float pr_[4] = {pv4.x, pv4.y, pv4.z, pv4.w};
      float4 jv[4];
#pragma unroll
      for (int u = 0; u < 4; ++u)
        jv[u] = *(const float4*)&jt[cur][dd * 1024 + u * 256 + lane * 4];
#pragma unroll
      for (int r = 0; r < 4; ++r) {
#pragma unroll
        for (int u = 0; u < 4; ++u) {
          acc[r][u*4+0] = fmaf(pr_[r], jv[u].x, acc[r][u*4+0]);
          acc[r][u*4+1] = fmaf(pr_[r], jv[u].y, acc[r][u*4+1]);
          acc[r][u*4+2] = fmaf(pr_[r], jv[u].z, acc[r][u*4+2]);
          acc[r][u*4+3] = fmaf(pr_[r], jv[u].w, acc[r][u*4+3]);
        }
      }
    }
    if (c < DPOS / DCH - 2) {
      const int nbuf = (cur + 2 >= 3) ? cur - 1 : cur + 2;
      JSTAGE(nbuf, c + 2);
      asm volatile("s_waitcnt vmcnt(2)" ::: "memory");
    } else {
      asm volatile("s_waitcnt vmcnt(0)" ::: "memory");
    }
    __syncthreads();
    cur = (cur + 1 >= 3) ? 0 : cur + 1;
  }
#undef JSTAGE

  float4 rv[4];
#pragma unroll
  for (int u = 0; u < 4; ++u) rv[u] = *(const float4*)&rnjL[u * 256 + lane * 4];

#pragma unroll
  for (int r = 0; r < 4; ++r) {
    const int rglob = w * 4 + r;
    const float sc = rnjL[i0 + rglob];
    float v[16];
#pragma unroll
    for (int u = 0; u < 4; ++u) {
      v[u*4+0] = acc[r][u*4+0] * rv[u].x * sc;
      v[u*4+1] = acc[r][u*4+1] * rv[u].y * sc;
      v[u*4+2] = acc[r][u*4+2] * rv[u].z * sc;
      v[u*4+3] = acc[r][u*4+3] * rv[u].w * sc;
    }
    int lo = 0;
#pragma unroll
    for (int bit = 16384; bit >= 1; bit >>= 1) {
      const float thrf = (float)(lo + bit) * QSTEP - 1.0f;
      int cnt = 0;
#pragma unroll
      for (int t = 0; t < 16; ++t) cnt += (int)__popcll(__ballot(v[t] >= thrf));
      if (cnt >= KSEL) lo += bit;
    }
    const float thr_h = (float)(lo + 1) * QSTEP - 1.0f;
    const float thr_l = (float)lo * QSTEP - 1.0f;
    int cbase = 0;
    unsigned cmask = 0u;
#pragma unroll
    for (int t = 0; t < 16; ++t) {
      const bool hi = (v[t] >= thr_h);
      const unsigned long long m = __ballot(hi);
      if (hi) {
        const int pos = cbase + (int)__builtin_amdgcn_mbcnt_hi(
            (unsigned)(m >> 32), __builtin_amdgcn_mbcnt_lo((unsigned)m, 0u));
        const int j = (t >> 2) * 256 + lane * 4 + (t & 3);
        *(float2*)&cand[rglob][2 * pos] = make_float2(v[t], __int_as_float(j));
      }
      cbase += (int)__popcll(m);
      if ((v[t] >= thr_l) && !hi) cmask |= (1u << t);
    }
    const int need = KSEL - cbase;
    for (int it = 0; it < need; ++it) {
      float bv = -2.0f; int bj = 0x7fffffff; int bt = 16;
#pragma unroll
      for (int t = 0; t < 16; ++t) {
        if (((cmask >> t) & 1u) && v[t] > bv) {
          bv = v[t]; bj = (t >> 2) * 256 + lane * 4 + (t & 3); bt = t;
        }
      }
      float rvv = bv; int rj = bj;
#pragma unroll
      for (int s = 1; s < 64; s <<= 1) {
        const float ov = __shfl_xor(rvv, s);
        const int   oj = __shfl_xor(rj, s);
        if (ov > rvv || (ov == rvv && oj < rj)) { rvv = ov; rj = oj; }
      }
      if (bv == rvv && bj == rj) {
        *(float2*)&cand[rglob][2 * (cbase + it)] = make_float2(bv, __int_as_float(bj));
        cmask &= ~(1u << bt);
      }
    }
    {
      const float x = cand[rglob][2 * (lane & 31)];
      float mx = x;
#pragma unroll
      for (int s = 16; s >= 1; s >>= 1) mx = fmaxf(mx, __shfl_xor(mx, s));
      const float e = expf(x - mx);
      float sum = e;
#pragma unroll
      for (int s = 16; s >= 1; s >>= 1) sum += __shfl_xor(sum, s);
      if (lane < KSEL) cand[rglob][2 * lane] = e / sum;
    }
  }
  __syncthreads();

  {
    const int pidx = tid * 2;
    const int r = pidx >> 5, k = pidx & 31;
    const float4 o4 = *(const float4*)&cand[r][2 * k];
    *(float4*)&pairs[((size_t)batch * NPTS + i0 + r) * KSEL + k] = o4;
  }
}

// ====== Kernel B: transposed-LDS gather, 128 rows/block (round-26) =========
// 512 blocks = 16 batch x 8 rowchunk x 4 ch-quarter. Block owns 128 rows x
// 64 channels; wave owns 16 channels, 4 passes of 4. Lane gathers FOUR
// row-slots (rs, +32, +64, +96) against the same staged tile -> staging
// traffic 256 MB -> 128 MB. Gather reads/lane unchanged (4x64 = 8x32).
// Transposed granule layout + khalf k-split identical to round-20 (proven).
__global__ __launch_bounds__(256, 2) void gnn_gather(const float* __restrict__ in,
                                                     const float2* __restrict__ pairs,
                                                     float* __restrict__ out) {
  __shared__ float fst[4][4096];       // per-wave 16 KB: 1024 granules x 16B

  const int p     = blockIdx.x;
  const int batch = ((p & 7) << 1) | ((p >> 3) & 1);   // 2 batches per XCD
  const int chunk = p >> 4;            // 0..31
  const int rchk  = chunk >> 2;        // 0..7 (128-row chunk)
  const int cq    = chunk & 3;         // channel quarter
  const int i0    = rchk * 128;
  const int tid   = threadIdx.x;
  const int w     = tid >> 6;
  const int lane  = tid & 63;
  const int rs    = lane & 31;         // row slots: i0+rs+{0,32,64,96}
  const int khalf = lane >> 5;
  const int ch0   = cq * 64 + w * 16;  // wave's 16 channels

  const float* __restrict__ fbase = in + (size_t)batch * CT * NPTS;
  float* const fw = &fst[w][0];

  // pairs for the four row-slots (khalf's 16 k each), swizzled byte offsets
  float aA[16], aB[16], aC[16], aD[16];
  int   jA[16], jB[16], jC[16], jD[16];
#define LDPAIRS(arr_a, arr_j, roff)                                              \
  do {                                                                           \
    const float4* pr4 = (const float4*)(pairs +                                  \
        ((size_t)batch * NPTS + i0 + (roff) + rs) * KSEL) + khalf * 8;           \
    _Pragma("unroll")                                                            \
    for (int qq = 0; qq < 8; ++qq) {                                             \
      const float4 o = pr4[qq];                                                  \
      const int d0 = __float_as_int(o.y), d1 = __float_as_int(o.w);              \
      arr_a[2*qq]   = o.x;                                                       \
      arr_j[2*qq]   = ((((d0 & 3) << 6) | ((d0 >> 2) & 63) | (d0 & ~255)) << 4); \
      arr_a[2*qq+1] = o.z;                                                       \
      arr_j[2*qq+1] = ((((d1 & 3) << 6) | ((d1 >> 2) & 63) | (d1 & ~255)) << 4); \
    }                                                                            \
  } while (0)
  LDPAIRS(aA, jA, 0);
  LDPAIRS(aB, jB, 32);
  LDPAIRS(aC, jC, 64);
  LDPAIRS(aD, jD, 96);
#undef LDPAIRS

  float4 tile[4][4];                   // [it][c], all indices compile-time

#define LOADT(pp)                                                                \
  do {                                                                           \
    _Pragma("unroll")                                                            \
    for (int it = 0; it < 4; ++it) {                                             \
      _Pragma("unroll")                                                          \
      for (int c = 0; c < 4; ++c)                                                \
        tile[it][c] = *(const float4*)(fbase +                                   \
            (size_t)(ch0 + (pp) * 4 + c) * NPTS + it * 256 + lane * 4);          \
    }                                                                            \
  } while (0)

#define WRITET()                                                                 \
  do {                                                                           \
    _Pragma("unroll")                                                            \
    for (int it = 0; it < 4; ++it) {                                             \
      *(float4*)&fw[(256*it + lane) * 4] =                                       \
          make_float4(tile[it][0].x, tile[it][1].x, tile[it][2].x, tile[it][3].x);\
      *(float4*)&fw[(256*it + 64 + lane) * 4] =                                  \
          make_float4(tile[it][0].y, tile[it][1].y, tile[it][2].y, tile[it][3].y);\
      *(float4*)&fw[(256*it + 128 + lane) * 4] =                                 \
          make_float4(tile[it][0].z, tile[it][1].z, tile[it][2].z, tile[it][3].z);\
      *(float4*)&fw[(256*it + 192 + lane) * 4] =                                 \
          make_float4(tile[it][0].w, tile[it][1].w, tile[it][2].w, tile[it][3].w);\
    }                                                                            \
  } while (0)

#define GATHER(arr_a, arr_j, ovar)                                               \
  do {                                                                           \
    _Pragma("unroll")                                                            \
    for (int kk = 0; kk < 16; ++kk) {                                            \
      const float4 f4 = *(const float4*)((const char*)fw + arr_j[kk]);           \
      const float ak = arr_a[kk];                                                \
      ovar.x = fmaf(ak, f4.x, ovar.x);                                           \
      ovar.y = fmaf(ak, f4.y, ovar.y);                                           \
      ovar.z = fmaf(ak, f4.z, ovar.z);                                           \
      ovar.w = fmaf(ak, f4.w, ovar.w);                                           \
    }                                                                            \
    ovar.x += __shfl_xor(ovar.x, 32);                                            \
    ovar.y += __shfl_xor(ovar.y, 32);                                            \
    ovar.z += __shfl_xor(ovar.z, 32);                                            \
    ovar.w += __shfl_xor(ovar.w, 32);                                            \
  } while (0)

  LOADT(0);
  WRITET();                            // compiler waits loads before first use

  for (int pp = 0; pp < 4; ++pp) {
    if (pp < 3) LOADT(pp + 1);         // issue next tile early (T14)

    float4 oA = make_float4(0.f, 0.f, 0.f, 0.f);
    float4 oB = make_float4(0.f, 0.f, 0.f, 0.f);
    float4 oC = make_float4(0.f, 0.f, 0.f, 0.f);
    float4 oD = make_float4(0.f, 0.f, 0.f, 0.f);
    GATHER(aA, jA, oA);
    GATHER(aB, jB, oB);
    GATHER(aC, jC, oC);
    GATHER(aD, jD, oD);

    float* ob = out + ((size_t)batch * DFEAT + ch0 + pp * 4) * NPTS + i0 + rs;
    if (khalf == 0) {
      ob[0]   = oA.x;  ob[(size_t)NPTS]      = oA.y;
      ob[32]  = oB.x;  ob[(size_t)NPTS + 32] = oB.y;
      ob[64]  = oC.x;  ob[(size_t)NPTS + 64] = oC.y;
      ob[96]  = oD.x;  ob[(size_t)NPTS + 96] = oD.y;
    } else {
      ob[(size_t)2 * NPTS]      = oA.z;  ob[(size_t)3 * NPTS]      = oA.w;
      ob[(size_t)2 * NPTS + 32] = oB.z;  ob[(size_t)3 * NPTS + 32] = oB.w;
      ob[(size_t)2 * NPTS + 64] = oC.z;  ob[(size_t)3 * NPTS + 64] = oC.w;
      ob[(size_t)2 * NPTS + 96] = oD.z;  ob[(size_t)3 * NPTS + 96] = oD.w;
    }

    if (pp < 3) WRITET();              // LDS write after gather reads (in-order DS)
  }
#undef LOADT
#undef WRITET
#undef GATHER
}

extern "C" void kernel_launch(void* const* d_in, const int* in_sizes, int n_in,
                              void* d_out, int out_size, void* d_ws, size_t ws_size,
                              hipStream_t stream) {
  const float* in = (const float*)d_in[0];
  float* out = (float*)d_out;
  float2* pairs = (float2*)d_ws;                           // 4 MB
  float*  rnjg  = (float*)((char*)d_ws + (16u << 20) / 4); // +4 MB: 64 KB table
  gnn_rnj<<<dim3(64), dim3(256), 0, stream>>>(in, rnjg);
  gnn_sim_topk<<<dim3(1024), dim3(256), 0, stream>>>(in, rnjg, pairs);
  gnn_gather<<<dim3(512), dim3(256), 0, stream>>>(in, pairs, out);
}

// Round 27
// 94.247 us; speedup vs baseline: 1.6982x; 1.6982x over previous
//
#include <hip/hip_runtime.h>
#include <math.h>

#define CT    320
#define NPTS  1024
#define DFEAT 256
#define DPOS  64
#define KSEL  32

// ============ Kernel C: per-point 1/max(||pos||,eps) -> rnjg (ws) ===========
__global__ void gnn_rnj(const float* __restrict__ in, float* __restrict__ rnjg) {
  const int b     = blockIdx.x;
  const int batch = b >> 2;
  const int j     = ((b & 3) << 8) + threadIdx.x;
  const float* __restrict__ pbase = in + (size_t)batch * CT * NPTS + (size_t)DFEAT * NPTS;
  float s = 0.f;
#pragma unroll 8
  for (int d = 0; d < DPOS; ++d) {
    const float x = pbase[(size_t)d * NPTS + j];
    s = fmaf(x, x, s);
  }
  rnjg[batch * NPTS + j] = 1.0f / fmaxf(sqrtf(s), 1e-12f);
}

// ================= Kernel A: round-11 config FROZEN (best: 64 us) ===========
#define AROWS 16
#define DCH   2
#define QSTEP 6.103515625e-05f          // 2^-14, thr(m) = m*QSTEP - 1 (exact)
__global__ __launch_bounds__(256, 4) void gnn_sim_topk(const float* __restrict__ in,
                                                       const float* __restrict__ rnjg,
                                                       float2* __restrict__ pairs) {
  __shared__ float pi[DPOS * 20];
  __shared__ float rnjL[NPTS];
  __shared__ float jt[3][DCH * 1024];
  __shared__ float cand[AROWS][68];

  const int p     = blockIdx.x;
  const int batch = ((p & 7) << 1) | ((p >> 3) & 1);
  const int chunk = p >> 4;
  const int i0    = chunk * AROWS;
  const int tid   = threadIdx.x;
  const int w     = tid >> 6;
  const int lane  = tid & 63;

  const float* __restrict__ pbase = in + (size_t)batch * CT * NPTS + (size_t)DFEAT * NPTS;

  {
    const int i = tid & 15;
    const int d0 = tid >> 4;
#pragma unroll
    for (int pass = 0; pass < 4; ++pass) {
      const int d = pass * 16 + d0;
      pi[d * 20 + i] = pbase[(size_t)d * NPTS + i0 + i];
    }
  }
  *(float4*)&rnjL[tid * 4] = *(const float4*)&rnjg[batch * NPTS + tid * 4];

#define JSTAGE(buf, c)                                                           \
  do {                                                                           \
    const int dd_   = (w >> 1);                                                  \
    const int half_ = (w & 1);                                                   \
    const float* src_ = pbase + (size_t)((c) * DCH + dd_) * NPTS + half_ * 512 + lane * 4; \
    float* dst_ = &jt[buf][dd_ * 1024 + half_ * 512];                            \
    __builtin_amdgcn_global_load_lds(                                            \
        (const __attribute__((address_space(1))) void*)(src_),                   \
        (__attribute__((address_space(3))) void*)(dst_), 16, 0, 0);              \
    __builtin_amdgcn_global_load_lds(                                            \
        (const __attribute__((address_space(1))) void*)(src_ + 256),             \
        (__attribute__((address_space(3))) void*)(dst_ + 256), 16, 0, 0);        \
  } while (0)

  JSTAGE(0, 0);
  JSTAGE(1, 1);
  asm volatile("s_waitcnt vmcnt(2)" ::: "memory");
  __syncthreads();

  float acc[4][16];
#pragma unroll
  for (int r = 0; r < 4; ++r)
#pragma unroll
    for (int s = 0; s < 16; ++s) acc[r][s] = 0.f;

  int cur = 0;
  for (int c = 0; c < DPOS / DCH; ++c) {
#pragma unroll
    for (int dd = 0; dd < DCH; ++dd) {
      const int d = c * DCH + dd;
      const float4 pv4 = *(const float4*)&pi[d * 20 + w * 4];
      const float pr_[4] = {pv4.x, pv4.y, pv4.z, pv4.w};
      float4 jv[4];
#pragma unroll
      for (int u = 0; u < 4; ++u)
        jv[u] = *(const float4*)&jt[cur][dd * 1024 + u * 256 + lane * 4];
#pragma unroll
      for (int r = 0; r < 4; ++r) {
#pragma unroll
        for (int u = 0; u < 4; ++u) {
          acc[r][u*4+0] = fmaf(pr_[r], jv[u].x, acc[r][u*4+0]);
          acc[r][u*4+1] = fmaf(pr_[r], jv[u].y, acc[r][u*4+1]);
          acc[r][u*4+2] = fmaf(pr_[r], jv[u].z, acc[r][u*4+2]);
          acc[r][u*4+3] = fmaf(pr_[r], jv[u].w, acc[r][u*4+3]);
        }
      }
    }
    if (c < DPOS / DCH - 2) {
      const int nbuf = (cur + 2 >= 3) ? cur - 1 : cur + 2;
      JSTAGE(nbuf, c + 2);
      asm volatile("s_waitcnt vmcnt(2)" ::: "memory");
    } else {
      asm volatile("s_waitcnt vmcnt(0)" ::: "memory");
    }
    __syncthreads();
    cur = (cur + 1 >= 3) ? 0 : cur + 1;
  }
#undef JSTAGE

  float4 rv[4];
#pragma unroll
  for (int u = 0; u < 4; ++u) rv[u] = *(const float4*)&rnjL[u * 256 + lane * 4];

#pragma unroll
  for (int r = 0; r < 4; ++r) {
    const int rglob = w * 4 + r;
    const float sc = rnjL[i0 + rglob];
    float v[16];
#pragma unroll
    for (int u = 0; u < 4; ++u) {
      v[u*4+0] = acc[r][u*4+0] * rv[u].x * sc;
      v[u*4+1] = acc[r][u*4+1] * rv[u].y * sc;
      v[u*4+2] = acc[r][u*4+2] * rv[u].z * sc;
      v[u*4+3] = acc[r][u*4+3] * rv[u].w * sc;
    }
    int lo = 0;
#pragma unroll
    for (int bit = 16384; bit >= 1; bit >>= 1) {
      const float thrf = (float)(lo + bit) * QSTEP - 1.0f;
      int cnt = 0;
#pragma unroll
      for (int t = 0; t < 16; ++t) cnt += (int)__popcll(__ballot(v[t] >= thrf));
      if (cnt >= KSEL) lo += bit;
    }
    const float thr_h = (float)(lo + 1) * QSTEP - 1.0f;
    const float thr_l = (float)lo * QSTEP - 1.0f;
    int cbase = 0;
    unsigned cmask = 0u;
#pragma unroll
    for (int t = 0; t < 16; ++t) {
      const bool hi = (v[t] >= thr_h);
      const unsigned long long m = __ballot(hi);
      if (hi) {
        const int pos = cbase + (int)__builtin_amdgcn_mbcnt_hi(
            (unsigned)(m >> 32), __builtin_amdgcn_mbcnt_lo((unsigned)m, 0u));
        const int j = (t >> 2) * 256 + lane * 4 + (t & 3);
        *(float2*)&cand[rglob][2 * pos] = make_float2(v[t], __int_as_float(j));
      }
      cbase += (int)__popcll(m);
      if ((v[t] >= thr_l) && !hi) cmask |= (1u << t);
    }
    const int need = KSEL - cbase;
    for (int it = 0; it < need; ++it) {
      float bv = -2.0f; int bj = 0x7fffffff; int bt = 16;
#pragma unroll
      for (int t = 0; t < 16; ++t) {
        if (((cmask >> t) & 1u) && v[t] > bv) {
          bv = v[t]; bj = (t >> 2) * 256 + lane * 4 + (t & 3); bt = t;
        }
      }
      float rvv = bv; int rj = bj;
#pragma unroll
      for (int s = 1; s < 64; s <<= 1) {
        const float ov = __shfl_xor(rvv, s);
        const int   oj = __shfl_xor(rj, s);
        if (ov > rvv || (ov == rvv && oj < rj)) { rvv = ov; rj = oj; }
      }
      if (bv == rvv && bj == rj) {
        *(float2*)&cand[rglob][2 * (cbase + it)] = make_float2(bv, __int_as_float(bj));
        cmask &= ~(1u << bt);
      }
    }
    {
      const float x = cand[rglob][2 * (lane & 31)];
      float mx = x;
#pragma unroll
      for (int s = 16; s >= 1; s >>= 1) mx = fmaxf(mx, __shfl_xor(mx, s));
      const float e = expf(x - mx);
      float sum = e;
#pragma unroll
      for (int s = 16; s >= 1; s >>= 1) sum += __shfl_xor(sum, s);
      if (lane < KSEL) cand[rglob][2 * lane] = e / sum;
    }
  }
  __syncthreads();

  {
    const int pidx = tid * 2;
    const int r = pidx >> 5, k = pidx & 31;
    const float4 o4 = *(const float4*)&cand[r][2 * k];
    *(float4*)&pairs[((size_t)batch * NPTS + i0 + r) * KSEL + k] = o4;
  }
}

// ====== Kernel B: transposed-LDS gather, 64 rows/block (round-25 FINAL) =====
// 512 blocks = 16 batch x 16 rowchunk x 2 chalf; wave owns 32 channels, 8
// passes of 4; lane gathers TWO row-slots against the same staged tile.
// Round-26's 4-slot variant spilled (128 pairs VGPRs -> 88 MB scratch writes,
// B 26->100 us) -- 2-slot is the VGPR-feasible optimum.
__global__ __launch_bounds__(256, 2) void gnn_gather(const float* __restrict__ in,
                                                     const float2* __restrict__ pairs,
                                                     float* __restrict__ out) {
  __shared__ float fst[4][4096];       // per-wave 16 KB: 1024 granules x 16B

  const int p     = blockIdx.x;
  const int batch = ((p & 7) << 1) | ((p >> 3) & 1);   // 2 batches per XCD
  const int chunk = p >> 4;            // 0..31
  const int rchk  = chunk >> 1;        // 0..15 (64-row chunk)
  const int chalf = chunk & 1;         // channel half
  const int i0    = rchk * 64;
  const int tid   = threadIdx.x;
  const int w     = tid >> 6;
  const int lane  = tid & 63;
  const int rs    = lane & 31;         // row slot: rows i0+rs, i0+32+rs
  const int khalf = lane >> 5;
  const int ch0   = chalf * 128 + w * 32;   // wave's 32 channels

  const float* __restrict__ fbase = in + (size_t)batch * CT * NPTS;
  float* const fw = &fst[w][0];

  // pairs for both row-slots (khalf's 16 k each), swizzled byte offsets
  float aA[16], aB[16]; int jA[16], jB[16];
  {
    const float4* prA = (const float4*)(pairs + ((size_t)batch * NPTS + i0 + rs) * KSEL)
                        + khalf * 8;
    const float4* prB = (const float4*)(pairs + ((size_t)batch * NPTS + i0 + 32 + rs) * KSEL)
                        + khalf * 8;
#pragma unroll
    for (int qq = 0; qq < 8; ++qq) {
      const float4 oA = prA[qq];
      const float4 oB = prB[qq];
      const int a0 = __float_as_int(oA.y), a1 = __float_as_int(oA.w);
      const int b0 = __float_as_int(oB.y), b1 = __float_as_int(oB.w);
      aA[2*qq]   = oA.x; jA[2*qq]   = ((((a0 & 3) << 6) | ((a0 >> 2) & 63) | (a0 & ~255)) << 4);
      aA[2*qq+1] = oA.z; jA[2*qq+1] = ((((a1 & 3) << 6) | ((a1 >> 2) & 63) | (a1 & ~255)) << 4);
      aB[2*qq]   = oB.x; jB[2*qq]   = ((((b0 & 3) << 6) | ((b0 >> 2) & 63) | (b0 & ~255)) << 4);
      aB[2*qq+1] = oB.z; jB[2*qq+1] = ((((b1 & 3) << 6) | ((b1 >> 2) & 63) | (b1 & ~255)) << 4);
    }
  }

  float4 tile[4][4];                   // [it][c], all indices compile-time

#define LOADT(pp)                                                                \
  do {                                                                           \
    _Pragma("unroll")                                                            \
    for (int it = 0; it < 4; ++it) {                                             \
      _Pragma("unroll")                                                          \
      for (int c = 0; c < 4; ++c)                                                \
        tile[it][c] = *(const float4*)(fbase +                                   \
            (size_t)(ch0 + (pp) * 4 + c) * NPTS + it * 256 + lane * 4);          \
    }                                                                            \
  } while (0)

#define WRITET()                                                                 \
  do {                                                                           \
    _Pragma("unroll")                                                            \
    for (int it = 0; it < 4; ++it) {                                             \
      *(float4*)&fw[(256*it + lane) * 4] =                                       \
          make_float4(tile[it][0].x, tile[it][1].x, tile[it][2].x, tile[it][3].x);\
      *(float4*)&fw[(256*it + 64 + lane) * 4] =                                  \
          make_float4(tile[it][0].y, tile[it][1].y, tile[it][2].y, tile[it][3].y);\
      *(float4*)&fw[(256*it + 128 + lane) * 4] =                                 \
          make_float4(tile[it][0].z, tile[it][1].z, tile[it][2].z, tile[it][3].z);\
      *(float4*)&fw[(256*it + 192 + lane) * 4] =                                 \
          make_float4(tile[it][0].w, tile[it][1].w, tile[it][2].w, tile[it][3].w);\
    }                                                                            \
  } while (0)

  LOADT(0);
  WRITET();                            // compiler waits loads before first use

  for (int pp = 0; pp < 8; ++pp) {
    if (pp < 7) LOADT(pp + 1);         // issue next tile early (T14)

    float4 oA4 = make_float4(0.f, 0.f, 0.f, 0.f);
    float4 oB4 = make_float4(0.f, 0.f, 0.f, 0.f);
#pragma unroll
    for (int kk = 0; kk < 16; ++kk) {
      const float4 fA = *(const float4*)((const char*)fw + jA[kk]);
      const float ak = aA[kk];
      oA4.x = fmaf(ak, fA.x, oA4.x);
      oA4.y = fmaf(ak, fA.y, oA4.y);
      oA4.z = fmaf(ak, fA.z, oA4.z);
      oA4.w = fmaf(ak, fA.w, oA4.w);
    }
#pragma unroll
    for (int kk = 0; kk < 16; ++kk) {
      const float4 fB = *(const float4*)((const char*)fw + jB[kk]);
      const float bk = aB[kk];
      oB4.x = fmaf(bk, fB.x, oB4.x);
      oB4.y = fmaf(bk, fB.y, oB4.y);
      oB4.z = fmaf(bk, fB.z, oB4.z);
      oB4.w = fmaf(bk, fB.w, oB4.w);
    }
    // combine k-halves (lane <-> lane+32, same rs); k order lo+hi as round-20
    oA4.x += __shfl_xor(oA4.x, 32);
    oA4.y += __shfl_xor(oA4.y, 32);
    oA4.z += __shfl_xor(oA4.z, 32);
    oA4.w += __shfl_xor(oA4.w, 32);
    oB4.x += __shfl_xor(oB4.x, 32);
    oB4.y += __shfl_xor(oB4.y, 32);
    oB4.z += __shfl_xor(oB4.z, 32);
    oB4.w += __shfl_xor(oB4.w, 32);

    float* obA = out + ((size_t)batch * DFEAT + ch0 + pp * 4) * NPTS + i0 + rs;
    float* obB = obA + 32;
    if (khalf == 0) {
      obA[0]            = oA4.x;
      obA[(size_t)NPTS] = oA4.y;
      obB[0]            = oB4.x;
      obB[(size_t)NPTS] = oB4.y;
    } else {
      obA[(size_t)2 * NPTS] = oA4.z;
      obA[(size_t)3 * NPTS] = oA4.w;
      obB[(size_t)2 * NPTS] = oB4.z;
      obB[(size_t)3 * NPTS] = oB4.w;
    }

    if (pp < 7) WRITET();              // LDS write after gather reads (in-order DS)
  }
#undef LOADT
#undef WRITET
}

extern "C" void kernel_launch(void* const* d_in, const int* in_sizes, int n_in,
                              void* d_out, int out_size, void* d_ws, size_t ws_size,
                              hipStream_t stream) {
  const float* in = (const float*)d_in[0];
  float* out = (float*)d_out;
  float2* pairs = (float2*)d_ws;                           // 4 MB
  float*  rnjg  = (float*)((char*)d_ws + (16u << 20) / 4); // +4 MB: 64 KB table
  gnn_rnj<<<dim3(64), dim3(256), 0, stream>>>(in, rnjg);
  gnn_sim_topk<<<dim3(1024), dim3(256), 0, stream>>>(in, rnjg, pairs);
  gnn_gather<<<dim3(512), dim3(256), 0, stream>>>(in, pairs, out);
}